// Round 2
// 842.009 us; speedup vs baseline: 1.0656x; 1.0656x over previous
//
#include <hip/hip_runtime.h>
#include <cmath>

// LinearGaussianChain v3b: k_pack rewritten as barrier-free, LDS-free
// streaming transpose using in-register 4x4 quad shuffles.
//  k_wf:     repack W -> bf16 B-frags; softplus table st[n][t] (t=0 -> 1.0)
//  k_prefix: per-chunk prefix matrices P_t (bf16 B-frags) for chunks 1..15
//  k_phase1: zero-start chunk chains -> x-temp (t-major fp32)
//  k_phase2: sequential boundary stitch -> h_c (c=1..15)
//  k_fix:    x_t += P_t * h_c  (independent per (c,t,mtile); no LDS)
//  k_pack:   wave-autonomous transpose (t,m,n)->(m,n,255-t) for x and m.
//            One wave = one (mm, 32-t tile). No LDS, no __syncthreads:
//            16 dwordx4 loads in flight, 4x4 transpose via __shfl_xor(16/32).
//  k_s:      s output from table (overwrites x-temp region last)
// x-temp lives in the s-output third of d_out (exact 134MB fit).

typedef __bf16 bf16x8 __attribute__((ext_vector_type(8)));
typedef float f32x4 __attribute__((ext_vector_type(4)));

#define XB_STRIDE 144  // bytes per LDS row: 64 bf16 + 16B pad

__device__ __forceinline__ float softplus_f(float z) {
  return (z > 20.0f) ? z : log1pf(expf(z));
}

// ---- k_wf: repack W (T,64,64) fp32 -> bf16 B-frag order; build s table ----
// Wf entry ((t*4+nt)*2+kh)*64+lane, lane=(q<<4)|n15 holds W[t][16nt+n15][32kh+8q+j]
__global__ void k_wf(const float* __restrict__ W, const float* __restrict__ ne,
                     bf16x8* __restrict__ Wf, float* __restrict__ st) {
  int t = blockIdx.x;
  for (int e = threadIdx.x; e < 512; e += blockDim.x) {
    int lane = e & 63;
    int kh = (e >> 6) & 1;
    int nt = e >> 7;
    int q = lane >> 4, n15 = lane & 15;
    int n = nt * 16 + n15;
    int k0 = kh * 32 + q * 8;
    const float* src = W + ((size_t)t * 64 + n) * 64 + k0;
    bf16x8 v;
#pragma unroll
    for (int j = 0; j < 8; ++j) v[j] = (__bf16)src[j];
    Wf[((size_t)(t * 4 + nt) * 2 + kh) * 64 + lane] = v;
  }
  if (threadIdx.x < 64) {
    int n = threadIdx.x;
    st[n * 256 + t] = (t == 0) ? 1.0f : softplus_f(ne[n * 256 + t]);
  }
}

// ---- k_prefix: chunk c=b+1, P_t = W_t * P_{t-1}, P starts at W_{16c}.
// Track Q = P^T (Q <- Q @ W_t^T), dump B-frags of P after every step. ----
__global__ __launch_bounds__(256) void k_prefix(const bf16x8* __restrict__ Wf,
                                                bf16x8* __restrict__ Pf) {
  __shared__ __align__(16) unsigned char Q[64 * XB_STRIDE];
  int b = blockIdx.x;  // 0..14, chunk c = b+1
  int c = b + 1;
  int tid = threadIdx.x;
  int lane = tid & 63, w = tid >> 6;
  int q = lane >> 4, n15 = lane & 15;
  int rbase = w * 16;
  for (int e = tid; e < 4096; e += 256) {
    int r = e >> 6, k = e & 63;
    *(__bf16*)(Q + r * XB_STRIDE + k * 2) = (__bf16)((r == k) ? 1.0f : 0.0f);
  }
  __syncthreads();
  for (int tl = 0; tl < 16; ++tl) {
    int t = c * 16 + tl;
    bf16x8 a0 = *(const bf16x8*)(Q + (rbase + n15) * XB_STRIDE + q * 16);
    bf16x8 a1 = *(const bf16x8*)(Q + (rbase + n15) * XB_STRIDE + 64 + q * 16);
    f32x4 acc[4];
#pragma unroll
    for (int nt = 0; nt < 4; ++nt) {
      bf16x8 b0 = Wf[((size_t)(t * 4 + nt) * 2 + 0) * 64 + lane];
      bf16x8 b1 = Wf[((size_t)(t * 4 + nt) * 2 + 1) * 64 + lane];
      f32x4 z = {0.f, 0.f, 0.f, 0.f};
      z = __builtin_amdgcn_mfma_f32_16x16x32_bf16(a0, b0, z, 0, 0, 0);
      z = __builtin_amdgcn_mfma_f32_16x16x32_bf16(a1, b1, z, 0, 0, 0);
      acc[nt] = z;
    }
#pragma unroll
    for (int nt = 0; nt < 4; ++nt)
#pragma unroll
      for (int reg = 0; reg < 4; ++reg)
        *(__bf16*)(Q + (rbase + 4 * q + reg) * XB_STRIDE + (nt * 16 + n15) * 2) =
            (__bf16)acc[nt][reg];
    __syncthreads();  // all rows updated before dump
    for (int e = tid; e < 512; e += 256) {
      int lane2 = e & 63;
      int kh = (e >> 6) & 1;
      int nt = e >> 7;
      int q2 = lane2 >> 4;
      int nn = nt * 16 + (lane2 & 15);
      bf16x8 v;
#pragma unroll
      for (int j = 0; j < 8; ++j)
        v[j] = *(const __bf16*)(Q + (kh * 32 + q2 * 8 + j) * XB_STRIDE + nn * 2);
      Pf[((size_t)(b * 16 + tl) * 8 + nt * 2 + kh) * 64 + lane2] = v;
    }
    __syncthreads();  // dump done before next overwrite
  }
}

// ---- k_phase1: zero-start chunk chains, x-temp t-major. 4 indep waves/block.
__global__ __launch_bounds__(256) void k_phase1(
    const float* __restrict__ bb, const float* __restrict__ st,
    const float* __restrict__ eps0, const float* __restrict__ eps,
    const bf16x8* __restrict__ Wf, float* __restrict__ xtemp) {
  __shared__ float stab[16][64];
  __shared__ float btab[16][64];
  __shared__ __align__(16) unsigned char xball[4 * 16 * XB_STRIDE];
  int tid = threadIdx.x, w = tid >> 6, lane = tid & 63;
  unsigned char* xb = xball + w * 16 * XB_STRIDE;
  int c = blockIdx.x >> 5;                     // 0..15
  int r0 = ((blockIdx.x & 31) * 4 + w) * 16;   // 16-row tile
  int q = lane >> 4, n15 = lane & 15;
  for (int e = tid; e < 1024; e += 256) {
    int tl = e >> 6, n = e & 63, t = c * 16 + tl;
    stab[tl][n] = st[n * 256 + t];
    btab[tl][n] = bb[t * 64 + n];
  }
  if (c == 0) {
    for (int i = 0; i < 16; ++i) {
      float v = eps0[(size_t)(r0 + i) * 64 + lane];
      *(__bf16*)(xb + i * XB_STRIDE + lane * 2) = (__bf16)v;
      xtemp[((size_t)(r0 + i)) * 64 + lane] = v;  // t=0
    }
  } else {
    for (int i = 0; i < 16; ++i)
      *(__bf16*)(xb + i * XB_STRIDE + lane * 2) = (__bf16)0.0f;
  }
  __syncthreads();  // stab/btab ready
  int t0 = (c == 0) ? 1 : c * 16;
  int t1 = c * 16 + 15;
  float epc[16], epn[16];
#pragma unroll
  for (int nt = 0; nt < 4; ++nt)
#pragma unroll
    for (int reg = 0; reg < 4; ++reg)
      epc[nt * 4 + reg] =
          eps[((size_t)(t0 - 1) * 2048 + r0 + 4 * q + reg) * 64 + nt * 16 + n15];
  for (int t = t0; t <= t1; ++t) {
    bool more = (t < t1);
    if (more) {
#pragma unroll
      for (int nt = 0; nt < 4; ++nt)
#pragma unroll
        for (int reg = 0; reg < 4; ++reg)
          epn[nt * 4 + reg] =
              eps[((size_t)t * 2048 + r0 + 4 * q + reg) * 64 + nt * 16 + n15];
    }
    bf16x8 a0 = *(const bf16x8*)(xb + n15 * XB_STRIDE + q * 16);
    bf16x8 a1 = *(const bf16x8*)(xb + n15 * XB_STRIDE + 64 + q * 16);
    f32x4 acc[4];
#pragma unroll
    for (int nt = 0; nt < 4; ++nt) {
      bf16x8 b0 = Wf[((size_t)(t * 4 + nt) * 2 + 0) * 64 + lane];
      bf16x8 b1 = Wf[((size_t)(t * 4 + nt) * 2 + 1) * 64 + lane];
      f32x4 z = {0.f, 0.f, 0.f, 0.f};
      z = __builtin_amdgcn_mfma_f32_16x16x32_bf16(a0, b0, z, 0, 0, 0);
      z = __builtin_amdgcn_mfma_f32_16x16x32_bf16(a1, b1, z, 0, 0, 0);
      acc[nt] = z;
    }
    int tl = t - c * 16;
#pragma unroll
    for (int nt = 0; nt < 4; ++nt) {
      int n = nt * 16 + n15;
      float sv = stab[tl][n];
      float bv = btab[tl][n];
#pragma unroll
      for (int reg = 0; reg < 4; ++reg) {
        int row = 4 * q + reg;
        float xn = acc[nt][reg] + bv + sv * epc[nt * 4 + reg];
        xtemp[((size_t)t * 2048 + r0 + row) * 64 + n] = xn;
        *(__bf16*)(xb + row * XB_STRIDE + n * 2) = (__bf16)xn;
      }
    }
    if (more) {
#pragma unroll
      for (int i = 0; i < 16; ++i) epc[i] = epn[i];
    }
  }
}

// ---- k_phase2: h_1 = x_15; h_{c+1} = tail_c + M_c h_c (M_c = P at chunk end)
__global__ __launch_bounds__(256) void k_phase2(const bf16x8* __restrict__ Pf,
                                                const float* __restrict__ xtemp,
                                                float* __restrict__ h) {
  __shared__ __align__(16) unsigned char hball[4 * 16 * XB_STRIDE];
  int tid = threadIdx.x, w = tid >> 6, lane = tid & 63;
  unsigned char* hb = hball + w * 16 * XB_STRIDE;
  int r0 = (blockIdx.x * 4 + w) * 16;
  int q = lane >> 4, n15 = lane & 15;
  for (int i = 0; i < 16; ++i) {
    float v = xtemp[((size_t)15 * 2048 + r0 + i) * 64 + lane];
    *(__bf16*)(hb + i * XB_STRIDE + lane * 2) = (__bf16)v;
    h[((size_t)1 * 2048 + r0 + i) * 64 + lane] = v;
  }
  for (int c = 1; c <= 14; ++c) {
    bf16x8 a0 = *(const bf16x8*)(hb + n15 * XB_STRIDE + q * 16);
    bf16x8 a1 = *(const bf16x8*)(hb + n15 * XB_STRIDE + 64 + q * 16);
    f32x4 acc[4];
#pragma unroll
    for (int nt = 0; nt < 4; ++nt) {
      bf16x8 b0 = Pf[((size_t)((c - 1) * 16 + 15) * 8 + nt * 2 + 0) * 64 + lane];
      bf16x8 b1 = Pf[((size_t)((c - 1) * 16 + 15) * 8 + nt * 2 + 1) * 64 + lane];
      f32x4 z = {0.f, 0.f, 0.f, 0.f};
      z = __builtin_amdgcn_mfma_f32_16x16x32_bf16(a0, b0, z, 0, 0, 0);
      z = __builtin_amdgcn_mfma_f32_16x16x32_bf16(a1, b1, z, 0, 0, 0);
      acc[nt] = z;
    }
#pragma unroll
    for (int nt = 0; nt < 4; ++nt) {
      int n = nt * 16 + n15;
#pragma unroll
      for (int reg = 0; reg < 4; ++reg) {
        int row = 4 * q + reg;
        float tail = xtemp[((size_t)(16 * c + 15) * 2048 + r0 + row) * 64 + n];
        float hn = acc[nt][reg] + tail;
        h[((size_t)(c + 1) * 2048 + r0 + row) * 64 + n] = hn;
        *(__bf16*)(hb + row * XB_STRIDE + n * 2) = (__bf16)hn;
      }
    }
  }
}

// ---- k_fix: x_t += P_t * h_c, independent per (c,t,mtile). No LDS. ----
__global__ __launch_bounds__(256) void k_fix(const bf16x8* __restrict__ Pf,
                                             const float* __restrict__ h,
                                             float* __restrict__ xtemp) {
  int tid = threadIdx.x, w = tid >> 6, lane = tid & 63;
  int r0 = (blockIdx.x & 31) * 64 + w * 16;
  int ct = blockIdx.x >> 5;  // 0..239
  int c1 = ct >> 4;
  int tl = ct & 15;
  int c = c1 + 1;
  int t = 16 * c + tl;
  int q = lane >> 4, n15 = lane & 15;
  const float* hrow = h + ((size_t)c * 2048 + r0 + n15) * 64;
  bf16x8 a0, a1;
#pragma unroll
  for (int j = 0; j < 8; ++j) {
    a0[j] = (__bf16)hrow[8 * q + j];
    a1[j] = (__bf16)hrow[32 + 8 * q + j];
  }
#pragma unroll
  for (int nt = 0; nt < 4; ++nt) {
    bf16x8 b0 = Pf[((size_t)(c1 * 16 + tl) * 8 + nt * 2 + 0) * 64 + lane];
    bf16x8 b1 = Pf[((size_t)(c1 * 16 + tl) * 8 + nt * 2 + 1) * 64 + lane];
    f32x4 z = {0.f, 0.f, 0.f, 0.f};
    z = __builtin_amdgcn_mfma_f32_16x16x32_bf16(a0, b0, z, 0, 0, 0);
    z = __builtin_amdgcn_mfma_f32_16x16x32_bf16(a1, b1, z, 0, 0, 0);
#pragma unroll
    for (int reg = 0; reg < 4; ++reg) {
      size_t idx = ((size_t)t * 2048 + r0 + 4 * q + reg) * 64 + nt * 16 + n15;
      xtemp[idx] += z[reg];
    }
  }
}

// ---- 4x4 transpose across lane quad {l, l+16, l+32, l+48} via shfl_xor ----
// Input: lane member L=(lane>>4) holds M[L][0..3]. Output: lane holds M[0..3][L].
__device__ __forceinline__ f32x4 quad_xpose4(f32x4 v, int L) {
  bool o1 = (L & 1) != 0;
  float sa = o1 ? v[0] : v[1];
  float sb = o1 ? v[2] : v[3];
  float ra = __shfl_xor(sa, 16, 64);
  float rb = __shfl_xor(sb, 16, 64);
  f32x4 u;
  u[0] = o1 ? ra : v[0];
  u[1] = o1 ? v[1] : ra;
  u[2] = o1 ? rb : v[2];
  u[3] = o1 ? v[3] : rb;
  bool o2 = (L & 2) != 0;
  float sc = o2 ? u[0] : u[2];
  float sd = o2 ? u[1] : u[3];
  float rc = __shfl_xor(sc, 32, 64);
  float rd = __shfl_xor(sd, 32, 64);
  f32x4 t;
  t[0] = o2 ? rc : u[0];
  t[1] = o2 ? rd : u[1];
  t[2] = o2 ? u[2] : rc;
  t[3] = o2 ? u[3] : rd;
  return t;
}

// ---- k_pack v3: wave-autonomous (t,m,n)->(m,n,255-t). No LDS, no barriers.
// One wave per (mm, 32-t tile): 16384 wave-tasks, 4 waves/block -> 4096 blocks.
// Consecutive waves take consecutive mm at the same t-tile -> contiguous reads.
__global__ __launch_bounds__(256) void k_pack(const float* __restrict__ st,
                                              const float* __restrict__ eps0,
                                              const float* __restrict__ eps,
                                              const float* __restrict__ xtemp,
                                              float* __restrict__ out) {
  int tid = threadIdx.x;
  int w = tid >> 6, lane = tid & 63;
  int task = blockIdx.x * 4 + w;
  int tile = task >> 11;  // 0..7
  int mm = task & 2047;
  int tt0 = tile * 32;
  int l15 = lane & 15, L = lane >> 4;
  int n0 = 4 * l15;
  int n = n0 + L;  // this lane's output row
  // s regs: st[n][tt0 .. tt0+31] (st has softplus applied; st[n][0]=1)
  f32x4 sr[8];
  const float* sp = st + n * 256 + tt0;
#pragma unroll
  for (int r = 0; r < 8; ++r) sr[r] = *(const f32x4*)(sp + 4 * r);
  // issue all 16 global loads (x + eps rows), 16B/lane each, before consuming
  f32x4 xr[8], er[8];
#pragma unroll
  for (int r = 0; r < 8; ++r) {
    int t = tt0 + 4 * r + L;  // this lane's source row
    xr[r] = *(const f32x4*)(xtemp + ((size_t)t * 2048 + mm) * 64 + n0);
    const float* erow = (t == 0) ? (eps0 + (size_t)mm * 64)
                                 : (eps + ((size_t)(t - 1) * 2048 + mm) * 64);
    er[r] = *(const f32x4*)(erow + n0);
  }
  size_t obase = ((size_t)mm * 64 + n) * 256;
  const size_t MSOFF = (size_t)2048 * 64 * 256;
#pragma unroll
  for (int r = 0; r < 8; ++r) {
    f32x4 xt = quad_xpose4(xr[r], L);  // now elem j = x(t=tt0+4r+j, n)
    f32x4 et = quad_xpose4(er[r], L);
    f32x4 mt = xt - sr[r] * et;   // mean = x - s*e (t=0: x - 1*eps0 = 0)
    // flip: out index i = 255 - t; float4 base at 252 - tt0 - 4r, reversed
    f32x4 xo = {xt[3], xt[2], xt[1], xt[0]};
    f32x4 mo = {mt[3], mt[2], mt[1], mt[0]};
    size_t o = obase + (size_t)(252 - tt0 - 4 * r);
    *(f32x4*)(out + o) = xo;
    *(f32x4*)(out + MSOFF + o) = mo;
  }
}

// ---- k_s: s output = table broadcast over m, t-flipped ----
__global__ __launch_bounds__(256) void k_s(const float* __restrict__ st,
                                           float* __restrict__ out) {
  int gid = blockIdx.x * 256 + threadIdx.x;  // 0..8388607
  int i0 = (gid & 63) * 4;
  int n = (gid >> 6) & 63;
  int m = gid >> 12;
  const float4 rv = *(const float4*)(st + n * 256 + 252 - i0);
  f32x4 v = {rv.w, rv.z, rv.y, rv.x};
  *(f32x4*)(out + (size_t)2 * 2048 * 64 * 256 + ((size_t)m * 64 + n) * 256 + i0) = v;
}

extern "C" void kernel_launch(void* const* d_in, const int* in_sizes, int n_in,
                              void* d_out, int out_size, void* d_ws, size_t ws_size,
                              hipStream_t stream) {
  const float* W = (const float*)d_in[0];     // (256,64,64)
  const float* bb = (const float*)d_in[1];    // (256,64)
  const float* ne = (const float*)d_in[2];    // (1,64,256)
  const float* eps0 = (const float*)d_in[3];  // (2048,64)
  const float* eps = (const float*)d_in[4];   // (255,2048,64)
  float* out = (float*)d_out;
  char* ws = (char*)d_ws;
  // ws layout: Wf 2MB | st 256KB | Pf 2MB | h 8MB  (~12.3 MB)
  bf16x8* Wf = (bf16x8*)ws;
  float* st = (float*)(ws + (size_t)(2u << 20));
  bf16x8* Pf = (bf16x8*)(ws + (size_t)(2u << 20) + (256u << 10));
  float* h = (float*)(ws + (size_t)(4u << 20) + (256u << 10));
  // x-temp (t-major, 134MB) lives in the s-output third of d_out.
  float* xtemp = out + (size_t)2 * 2048 * 64 * 256;

  hipLaunchKernelGGL(k_wf, dim3(256), dim3(256), 0, stream, W, ne, Wf, st);
  hipLaunchKernelGGL(k_prefix, dim3(15), dim3(256), 0, stream, Wf, Pf);
  hipLaunchKernelGGL(k_phase1, dim3(512), dim3(256), 0, stream, bb, st, eps0, eps, Wf, xtemp);
  hipLaunchKernelGGL(k_phase2, dim3(32), dim3(256), 0, stream, Pf, xtemp, h);
  hipLaunchKernelGGL(k_fix, dim3(7680), dim3(256), 0, stream, Pf, h, xtemp);
  hipLaunchKernelGGL(k_pack, dim3(4096), dim3(256), 0, stream, st, eps0, eps, xtemp, out);
  hipLaunchKernelGGL(k_s, dim3(32768), dim3(256), 0, stream, st, out);
}

// Round 3
// 673.297 us; speedup vs baseline: 1.3326x; 1.2506x over previous
//
#include <hip/hip_runtime.h>
#include <cmath>

// LinearGaussianChain v4: kill sub-line scatter transactions.
//  k_pack: LDS-staged store coalescing (8x128B segments per store instr,
//          was 64x16B). No barriers (wave-private LDS, DS ops in-order).
//          No shuffles: m = x - s*e computed in t-row orientation via stT.
//  k_fix:  A-operand read as 2x b128 from hA (bf16 A-frags dumped by
//          k_phase2), was 16 scattered dword loads + cvt per lane.
//  k_phase2: dumps hA (replaces f32 h buffer entirely).
// x-temp lives in the s-output third of d_out (exact 134MB fit).

typedef __bf16 bf16x8 __attribute__((ext_vector_type(8)));
typedef float f32x4 __attribute__((ext_vector_type(4)));

#define XB_STRIDE 144  // bytes per LDS row: 64 bf16 + 16B pad

__device__ __forceinline__ float softplus_f(float z) {
  return (z > 20.0f) ? z : log1pf(expf(z));
}

// ---- k_wf: repack W (T,64,64) fp32 -> bf16 B-frag order; build s tables ----
// Wf entry ((t*4+nt)*2+kh)*64+lane, lane=(q<<4)|n15 holds W[t][16nt+n15][32kh+8q+j]
__global__ void k_wf(const float* __restrict__ W, const float* __restrict__ ne,
                     bf16x8* __restrict__ Wf, float* __restrict__ st,
                     float* __restrict__ stT) {
  int t = blockIdx.x;
  for (int e = threadIdx.x; e < 512; e += blockDim.x) {
    int lane = e & 63;
    int kh = (e >> 6) & 1;
    int nt = e >> 7;
    int q = lane >> 4, n15 = lane & 15;
    int n = nt * 16 + n15;
    int k0 = kh * 32 + q * 8;
    const float* src = W + ((size_t)t * 64 + n) * 64 + k0;
    bf16x8 v;
#pragma unroll
    for (int j = 0; j < 8; ++j) v[j] = (__bf16)src[j];
    Wf[((size_t)(t * 4 + nt) * 2 + kh) * 64 + lane] = v;
  }
  if (threadIdx.x < 64) {
    int n = threadIdx.x;
    float v = (t == 0) ? 1.0f : softplus_f(ne[n * 256 + t]);
    st[n * 256 + t] = v;
    stT[t * 64 + n] = v;
  }
}

// ---- k_prefix: chunk c=b+1, P_t = W_t * P_{t-1}, P starts at W_{16c}.
// Track Q = P^T (Q <- Q @ W_t^T), dump B-frags of P after every step. ----
__global__ __launch_bounds__(256) void k_prefix(const bf16x8* __restrict__ Wf,
                                                bf16x8* __restrict__ Pf) {
  __shared__ __align__(16) unsigned char Q[64 * XB_STRIDE];
  int b = blockIdx.x;  // 0..14, chunk c = b+1
  int c = b + 1;
  int tid = threadIdx.x;
  int lane = tid & 63, w = tid >> 6;
  int q = lane >> 4, n15 = lane & 15;
  int rbase = w * 16;
  for (int e = tid; e < 4096; e += 256) {
    int r = e >> 6, k = e & 63;
    *(__bf16*)(Q + r * XB_STRIDE + k * 2) = (__bf16)((r == k) ? 1.0f : 0.0f);
  }
  __syncthreads();
  for (int tl = 0; tl < 16; ++tl) {
    int t = c * 16 + tl;
    bf16x8 a0 = *(const bf16x8*)(Q + (rbase + n15) * XB_STRIDE + q * 16);
    bf16x8 a1 = *(const bf16x8*)(Q + (rbase + n15) * XB_STRIDE + 64 + q * 16);
    f32x4 acc[4];
#pragma unroll
    for (int nt = 0; nt < 4; ++nt) {
      bf16x8 b0 = Wf[((size_t)(t * 4 + nt) * 2 + 0) * 64 + lane];
      bf16x8 b1 = Wf[((size_t)(t * 4 + nt) * 2 + 1) * 64 + lane];
      f32x4 z = {0.f, 0.f, 0.f, 0.f};
      z = __builtin_amdgcn_mfma_f32_16x16x32_bf16(a0, b0, z, 0, 0, 0);
      z = __builtin_amdgcn_mfma_f32_16x16x32_bf16(a1, b1, z, 0, 0, 0);
      acc[nt] = z;
    }
#pragma unroll
    for (int nt = 0; nt < 4; ++nt)
#pragma unroll
      for (int reg = 0; reg < 4; ++reg)
        *(__bf16*)(Q + (rbase + 4 * q + reg) * XB_STRIDE + (nt * 16 + n15) * 2) =
            (__bf16)acc[nt][reg];
    __syncthreads();  // all rows updated before dump
    for (int e = tid; e < 512; e += 256) {
      int lane2 = e & 63;
      int kh = (e >> 6) & 1;
      int nt = e >> 7;
      int q2 = lane2 >> 4;
      int nn = nt * 16 + (lane2 & 15);
      bf16x8 v;
#pragma unroll
      for (int j = 0; j < 8; ++j)
        v[j] = *(const __bf16*)(Q + (kh * 32 + q2 * 8 + j) * XB_STRIDE + nn * 2);
      Pf[((size_t)(b * 16 + tl) * 8 + nt * 2 + kh) * 64 + lane2] = v;
    }
    __syncthreads();  // dump done before next overwrite
  }
}

// ---- k_phase1: zero-start chunk chains, x-temp t-major. 4 indep waves/block.
__global__ __launch_bounds__(256) void k_phase1(
    const float* __restrict__ bb, const float* __restrict__ st,
    const float* __restrict__ eps0, const float* __restrict__ eps,
    const bf16x8* __restrict__ Wf, float* __restrict__ xtemp) {
  __shared__ float stab[16][64];
  __shared__ float btab[16][64];
  __shared__ __align__(16) unsigned char xball[4 * 16 * XB_STRIDE];
  int tid = threadIdx.x, w = tid >> 6, lane = tid & 63;
  unsigned char* xb = xball + w * 16 * XB_STRIDE;
  int c = blockIdx.x >> 5;                     // 0..15
  int r0 = ((blockIdx.x & 31) * 4 + w) * 16;   // 16-row tile
  int q = lane >> 4, n15 = lane & 15;
  for (int e = tid; e < 1024; e += 256) {
    int tl = e >> 6, n = e & 63, t = c * 16 + tl;
    stab[tl][n] = st[n * 256 + t];
    btab[tl][n] = bb[t * 64 + n];
  }
  if (c == 0) {
    for (int i = 0; i < 16; ++i) {
      float v = eps0[(size_t)(r0 + i) * 64 + lane];
      *(__bf16*)(xb + i * XB_STRIDE + lane * 2) = (__bf16)v;
      xtemp[((size_t)(r0 + i)) * 64 + lane] = v;  // t=0
    }
  } else {
    for (int i = 0; i < 16; ++i)
      *(__bf16*)(xb + i * XB_STRIDE + lane * 2) = (__bf16)0.0f;
  }
  __syncthreads();  // stab/btab ready
  int t0 = (c == 0) ? 1 : c * 16;
  int t1 = c * 16 + 15;
  float epc[16], epn[16];
#pragma unroll
  for (int nt = 0; nt < 4; ++nt)
#pragma unroll
    for (int reg = 0; reg < 4; ++reg)
      epc[nt * 4 + reg] =
          eps[((size_t)(t0 - 1) * 2048 + r0 + 4 * q + reg) * 64 + nt * 16 + n15];
  for (int t = t0; t <= t1; ++t) {
    bool more = (t < t1);
    if (more) {
#pragma unroll
      for (int nt = 0; nt < 4; ++nt)
#pragma unroll
        for (int reg = 0; reg < 4; ++reg)
          epn[nt * 4 + reg] =
              eps[((size_t)t * 2048 + r0 + 4 * q + reg) * 64 + nt * 16 + n15];
    }
    bf16x8 a0 = *(const bf16x8*)(xb + n15 * XB_STRIDE + q * 16);
    bf16x8 a1 = *(const bf16x8*)(xb + n15 * XB_STRIDE + 64 + q * 16);
    f32x4 acc[4];
#pragma unroll
    for (int nt = 0; nt < 4; ++nt) {
      bf16x8 b0 = Wf[((size_t)(t * 4 + nt) * 2 + 0) * 64 + lane];
      bf16x8 b1 = Wf[((size_t)(t * 4 + nt) * 2 + 1) * 64 + lane];
      f32x4 z = {0.f, 0.f, 0.f, 0.f};
      z = __builtin_amdgcn_mfma_f32_16x16x32_bf16(a0, b0, z, 0, 0, 0);
      z = __builtin_amdgcn_mfma_f32_16x16x32_bf16(a1, b1, z, 0, 0, 0);
      acc[nt] = z;
    }
    int tl = t - c * 16;
#pragma unroll
    for (int nt = 0; nt < 4; ++nt) {
      int n = nt * 16 + n15;
      float sv = stab[tl][n];
      float bv = btab[tl][n];
#pragma unroll
      for (int reg = 0; reg < 4; ++reg) {
        int row = 4 * q + reg;
        float xn = acc[nt][reg] + bv + sv * epc[nt * 4 + reg];
        xtemp[((size_t)t * 2048 + r0 + row) * 64 + n] = xn;
        *(__bf16*)(xb + row * XB_STRIDE + n * 2) = (__bf16)xn;
      }
    }
    if (more) {
#pragma unroll
      for (int i = 0; i < 16; ++i) epc[i] = epn[i];
    }
  }
}

// ---- k_phase2: h_1 = x_15; h_{c+1} = tail_c + M_c h_c. Dumps bf16 A-frags
// hA[c] for c=1..15 (exactly the frags k_fix consumes). No f32 h buffer. ----
__global__ __launch_bounds__(256) void k_phase2(const bf16x8* __restrict__ Pf,
                                                const float* __restrict__ xtemp,
                                                bf16x8* __restrict__ hA) {
  __shared__ __align__(16) unsigned char hball[4 * 16 * XB_STRIDE];
  int tid = threadIdx.x, w = tid >> 6, lane = tid & 63;
  unsigned char* hb = hball + w * 16 * XB_STRIDE;
  int rtile = blockIdx.x * 4 + w;  // 0..127
  int r0 = rtile * 16;
  int q = lane >> 4, n15 = lane & 15;
  for (int i = 0; i < 16; ++i) {
    float v = xtemp[((size_t)15 * 2048 + r0 + i) * 64 + lane];
    *(__bf16*)(hb + i * XB_STRIDE + lane * 2) = (__bf16)v;
  }
  for (int c = 1; c <= 15; ++c) {
    bf16x8 a0 = *(const bf16x8*)(hb + n15 * XB_STRIDE + q * 16);
    bf16x8 a1 = *(const bf16x8*)(hb + n15 * XB_STRIDE + 64 + q * 16);
    size_t hbase = ((size_t)(c - 1) * 128 + rtile) * 128;
    hA[hbase + lane] = a0;
    hA[hbase + 64 + lane] = a1;
    if (c == 15) break;
    f32x4 acc[4];
#pragma unroll
    for (int nt = 0; nt < 4; ++nt) {
      bf16x8 b0 = Pf[((size_t)((c - 1) * 16 + 15) * 8 + nt * 2 + 0) * 64 + lane];
      bf16x8 b1 = Pf[((size_t)((c - 1) * 16 + 15) * 8 + nt * 2 + 1) * 64 + lane];
      f32x4 z = {0.f, 0.f, 0.f, 0.f};
      z = __builtin_amdgcn_mfma_f32_16x16x32_bf16(a0, b0, z, 0, 0, 0);
      z = __builtin_amdgcn_mfma_f32_16x16x32_bf16(a1, b1, z, 0, 0, 0);
      acc[nt] = z;
    }
#pragma unroll
    for (int nt = 0; nt < 4; ++nt) {
      int n = nt * 16 + n15;
#pragma unroll
      for (int reg = 0; reg < 4; ++reg) {
        int row = 4 * q + reg;
        float tail = xtemp[((size_t)(16 * c + 15) * 2048 + r0 + row) * 64 + n];
        float hn = acc[nt][reg] + tail;
        *(__bf16*)(hb + row * XB_STRIDE + n * 2) = (__bf16)hn;
      }
    }
  }
}

// ---- k_fix: x_t += P_t * h_c. A-operand = 2x b128 from hA. ----
__global__ __launch_bounds__(256) void k_fix(const bf16x8* __restrict__ Pf,
                                             const bf16x8* __restrict__ hA,
                                             float* __restrict__ xtemp) {
  int tid = threadIdx.x, w = tid >> 6, lane = tid & 63;
  int rtile = (blockIdx.x & 31) * 4 + w;  // 0..127
  int r0 = rtile * 16;
  int ct = blockIdx.x >> 5;  // 0..239
  int c1 = ct >> 4;
  int tl = ct & 15;
  int c = c1 + 1;
  int t = 16 * c + tl;
  int q = lane >> 4, n15 = lane & 15;
  size_t hbase = ((size_t)c1 * 128 + rtile) * 128;
  bf16x8 a0 = hA[hbase + lane];
  bf16x8 a1 = hA[hbase + 64 + lane];
#pragma unroll
  for (int nt = 0; nt < 4; ++nt) {
    bf16x8 b0 = Pf[((size_t)(c1 * 16 + tl) * 8 + nt * 2 + 0) * 64 + lane];
    bf16x8 b1 = Pf[((size_t)(c1 * 16 + tl) * 8 + nt * 2 + 1) * 64 + lane];
    f32x4 z = {0.f, 0.f, 0.f, 0.f};
    z = __builtin_amdgcn_mfma_f32_16x16x32_bf16(a0, b0, z, 0, 0, 0);
    z = __builtin_amdgcn_mfma_f32_16x16x32_bf16(a1, b1, z, 0, 0, 0);
#pragma unroll
    for (int reg = 0; reg < 4; ++reg) {
      size_t idx = ((size_t)t * 2048 + r0 + 4 * q + reg) * 64 + nt * 16 + n15;
      xtemp[idx] += z[reg];
    }
  }
}

// ---- k_pack v4: wave-autonomous (t,m,n)->(m,n,255-t) with LDS-staged
// coalesced stores. One wave = one (mm, 32-t tile). No barriers: DS ops
// from one wave execute in order; LDS slice is wave-private.
// Reads: 1KB/instr contiguous. Stores: 8 rows x 128B full lines per instr.
__global__ __launch_bounds__(256) void k_pack(const float* __restrict__ stT,
                                              const float* __restrict__ eps0,
                                              const float* __restrict__ eps,
                                              const float* __restrict__ xtemp,
                                              float* __restrict__ out) {
  __shared__ __align__(16) float lds[4][64 * 36];  // [n][32 i + 4 pad] per wave
  int tid = threadIdx.x;
  int w = tid >> 6, lane = tid & 63;
  float* wls = lds[w];
  int task = blockIdx.x * 4 + w;
  int tile = task >> 11;  // 0..7
  int mm = task & 2047;
  int tt0 = tile * 32;
  int iblk0 = 224 - tt0;  // output i-base of this tile's 32-float block
  int l15 = lane & 15, L = lane >> 4;
  int n0 = 4 * l15;
  // load phase: lane (l15,L) reads x/eps rows t = tt0+4r+L, n0..n0+3
  f32x4 xr[8], er[8];
#pragma unroll
  for (int r = 0; r < 8; ++r) {
    int t = tt0 + 4 * r + L;
    xr[r] = *(const f32x4*)(xtemp + ((size_t)t * 2048 + mm) * 64 + n0);
    const float* erow = (t == 0) ? (eps0 + (size_t)mm * 64)
                                 : (eps + ((size_t)(t - 1) * 2048 + mm) * 64);
    er[r] = *(const f32x4*)(erow + n0);
  }
  // m = x - s*e in original orientation (stT is t-major, L1/L2-hot 64KB)
#pragma unroll
  for (int r = 0; r < 8; ++r) {
    int t = tt0 + 4 * r + L;
    f32x4 s = *(const f32x4*)(stT + (size_t)t * 64 + n0);
    er[r] = xr[r] - s * er[r];  // er now holds m; t=0 -> x - 1*eps0 = 0
  }
  int nrd = lane >> 3;        // output row within 8-row group
  int crd = (lane & 7) * 4;   // float offset within 32-float block
  const size_t MSOFF = (size_t)2048 * 64 * 256;
  size_t obase = ((size_t)mm * 64) * 256 + (size_t)(iblk0 + crd);
  // ---- x: stage (flip t->i) then store coalesced ----
#pragma unroll
  for (int r = 0; r < 8; ++r) {
    int col = 31 - 4 * r - L;  // i - iblk0
#pragma unroll
    for (int j = 0; j < 4; ++j) wls[(n0 + j) * 36 + col] = xr[r][j];
  }
#pragma unroll
  for (int jj = 0; jj < 8; ++jj) {
    int nn = 8 * jj + nrd;
    f32x4 v = *(const f32x4*)(wls + nn * 36 + crd);
    *(f32x4*)(out + obase + (size_t)nn * 256) = v;
  }
  // ---- m: reuse the same LDS slice (DS in-order per wave) ----
#pragma unroll
  for (int r = 0; r < 8; ++r) {
    int col = 31 - 4 * r - L;
#pragma unroll
    for (int j = 0; j < 4; ++j) wls[(n0 + j) * 36 + col] = er[r][j];
  }
#pragma unroll
  for (int jj = 0; jj < 8; ++jj) {
    int nn = 8 * jj + nrd;
    f32x4 v = *(const f32x4*)(wls + nn * 36 + crd);
    *(f32x4*)(out + MSOFF + obase + (size_t)nn * 256) = v;
  }
}

// ---- k_s: s output = table broadcast over m, t-flipped ----
__global__ __launch_bounds__(256) void k_s(const float* __restrict__ st,
                                           float* __restrict__ out) {
  int gid = blockIdx.x * 256 + threadIdx.x;  // 0..8388607
  int i0 = (gid & 63) * 4;
  int n = (gid >> 6) & 63;
  int m = gid >> 12;
  const float4 rv = *(const float4*)(st + n * 256 + 252 - i0);
  f32x4 v = {rv.w, rv.z, rv.y, rv.x};
  *(f32x4*)(out + (size_t)2 * 2048 * 64 * 256 + ((size_t)m * 64 + n) * 256 + i0) = v;
}

extern "C" void kernel_launch(void* const* d_in, const int* in_sizes, int n_in,
                              void* d_out, int out_size, void* d_ws, size_t ws_size,
                              hipStream_t stream) {
  const float* W = (const float*)d_in[0];     // (256,64,64)
  const float* bb = (const float*)d_in[1];    // (256,64)
  const float* ne = (const float*)d_in[2];    // (1,64,256)
  const float* eps0 = (const float*)d_in[3];  // (2048,64)
  const float* eps = (const float*)d_in[4];   // (255,2048,64)
  float* out = (float*)d_out;
  char* ws = (char*)d_ws;
  // ws layout: Wf 2MB | st 128KB | stT 128KB | Pf 2MB | hA 4MB  (~8.25 MB)
  bf16x8* Wf = (bf16x8*)ws;
  float* st = (float*)(ws + (size_t)(2u << 20));
  float* stT = (float*)(ws + (size_t)(2u << 20) + (128u << 10));
  bf16x8* Pf = (bf16x8*)(ws + (size_t)(2u << 20) + (256u << 10));
  bf16x8* hA = (bf16x8*)(ws + (size_t)(4u << 20) + (256u << 10));
  // x-temp (t-major, 134MB) lives in the s-output third of d_out.
  float* xtemp = out + (size_t)2 * 2048 * 64 * 256;

  hipLaunchKernelGGL(k_wf, dim3(256), dim3(256), 0, stream, W, ne, Wf, st, stT);
  hipLaunchKernelGGL(k_prefix, dim3(15), dim3(256), 0, stream, Wf, Pf);
  hipLaunchKernelGGL(k_phase1, dim3(512), dim3(256), 0, stream, bb, st, eps0, eps, Wf, xtemp);
  hipLaunchKernelGGL(k_phase2, dim3(32), dim3(256), 0, stream, Pf, xtemp, hA);
  hipLaunchKernelGGL(k_fix, dim3(7680), dim3(256), 0, stream, Pf, hA, xtemp);
  hipLaunchKernelGGL(k_pack, dim3(4096), dim3(256), 0, stream, stT, eps0, eps, xtemp, out);
  hipLaunchKernelGGL(k_s, dim3(32768), dim3(256), 0, stream, st, out);
}

// Round 5
// 664.250 us; speedup vs baseline: 1.3508x; 1.0136x over previous
//
#include <hip/hip_runtime.h>
#include <cmath>

// LinearGaussianChain v6: v5 (transaction-width + LDS-swizzle pass) with the
// staged-LDS ordering hazard fixed:
//  - staged reads are scalar float (same TBAA type as the writes), assembled
//    into f32x4 registers for the vector global store;
//  - asm volatile("" ::: "memory") fences at each write->read phase boundary.
//  k_pack:   staging LDS [64][32] XOR-swizzled, 8KB/wave, no barriers.
//  k_fix:    MFMA corr restaged via swizzled LDS -> 4x contiguous 1KB RMW.
//  k_phase1: xtemp stores restaged the same way (16 scalar -> 4x 1KB).
// x-temp lives in the s-output third of d_out (exact 134MB fit).

typedef __bf16 bf16x8 __attribute__((ext_vector_type(8)));
typedef float f32x4 __attribute__((ext_vector_type(4)));

#define XB_STRIDE 144  // bytes per LDS row: 64 bf16 + 16B pad

// [16 rows][64 cols] f32 stage: row XOR breaks stride-64 (mod-32=0) aliasing.
#define SWA(row, col) ((row)*64 + ((col) ^ ((((row)) & 7) << 2)))
// [64 rows][32 cols] f32 stage for k_pack: row>>2 carries l15 into banks.
#define SWP(row, col) ((row)*32 + ((col) ^ ((((row) >> 2) & 7) << 2)))

__device__ __forceinline__ float softplus_f(float z) {
  return (z > 20.0f) ? z : log1pf(expf(z));
}

// ---- k_wf: repack W (T,64,64) fp32 -> bf16 B-frag order; build s tables ----
// Wf entry ((t*4+nt)*2+kh)*64+lane, lane=(q<<4)|n15 holds W[t][16nt+n15][32kh+8q+j]
__global__ void k_wf(const float* __restrict__ W, const float* __restrict__ ne,
                     bf16x8* __restrict__ Wf, float* __restrict__ st,
                     float* __restrict__ stT) {
  int t = blockIdx.x;
  for (int e = threadIdx.x; e < 512; e += blockDim.x) {
    int lane = e & 63;
    int kh = (e >> 6) & 1;
    int nt = e >> 7;
    int q = lane >> 4, n15 = lane & 15;
    int n = nt * 16 + n15;
    int k0 = kh * 32 + q * 8;
    const float* src = W + ((size_t)t * 64 + n) * 64 + k0;
    bf16x8 v;
#pragma unroll
    for (int j = 0; j < 8; ++j) v[j] = (__bf16)src[j];
    Wf[((size_t)(t * 4 + nt) * 2 + kh) * 64 + lane] = v;
  }
  if (threadIdx.x < 64) {
    int n = threadIdx.x;
    float v = (t == 0) ? 1.0f : softplus_f(ne[n * 256 + t]);
    st[n * 256 + t] = v;
    stT[t * 64 + n] = v;
  }
}

// ---- k_prefix: chunk c=b+1, P_t = W_t * P_{t-1}, P starts at W_{16c}.
// Track Q = P^T (Q <- Q @ W_t^T), dump B-frags of P after every step. ----
__global__ __launch_bounds__(256) void k_prefix(const bf16x8* __restrict__ Wf,
                                                bf16x8* __restrict__ Pf) {
  __shared__ __align__(16) unsigned char Q[64 * XB_STRIDE];
  int b = blockIdx.x;  // 0..14, chunk c = b+1
  int c = b + 1;
  int tid = threadIdx.x;
  int lane = tid & 63, w = tid >> 6;
  int q = lane >> 4, n15 = lane & 15;
  int rbase = w * 16;
  for (int e = tid; e < 4096; e += 256) {
    int r = e >> 6, k = e & 63;
    *(__bf16*)(Q + r * XB_STRIDE + k * 2) = (__bf16)((r == k) ? 1.0f : 0.0f);
  }
  __syncthreads();
  for (int tl = 0; tl < 16; ++tl) {
    int t = c * 16 + tl;
    bf16x8 a0 = *(const bf16x8*)(Q + (rbase + n15) * XB_STRIDE + q * 16);
    bf16x8 a1 = *(const bf16x8*)(Q + (rbase + n15) * XB_STRIDE + 64 + q * 16);
    f32x4 acc[4];
#pragma unroll
    for (int nt = 0; nt < 4; ++nt) {
      bf16x8 b0 = Wf[((size_t)(t * 4 + nt) * 2 + 0) * 64 + lane];
      bf16x8 b1 = Wf[((size_t)(t * 4 + nt) * 2 + 1) * 64 + lane];
      f32x4 z = {0.f, 0.f, 0.f, 0.f};
      z = __builtin_amdgcn_mfma_f32_16x16x32_bf16(a0, b0, z, 0, 0, 0);
      z = __builtin_amdgcn_mfma_f32_16x16x32_bf16(a1, b1, z, 0, 0, 0);
      acc[nt] = z;
    }
#pragma unroll
    for (int nt = 0; nt < 4; ++nt)
#pragma unroll
      for (int reg = 0; reg < 4; ++reg)
        *(__bf16*)(Q + (rbase + 4 * q + reg) * XB_STRIDE + (nt * 16 + n15) * 2) =
            (__bf16)acc[nt][reg];
    __syncthreads();  // all rows updated before dump
    for (int e = tid; e < 512; e += 256) {
      int lane2 = e & 63;
      int kh = (e >> 6) & 1;
      int nt = e >> 7;
      int q2 = lane2 >> 4;
      int nn = nt * 16 + (lane2 & 15);
      bf16x8 v;
#pragma unroll
      for (int j = 0; j < 8; ++j)
        v[j] = *(const __bf16*)(Q + (kh * 32 + q2 * 8 + j) * XB_STRIDE + nn * 2);
      Pf[((size_t)(b * 16 + tl) * 8 + nt * 2 + kh) * 64 + lane2] = v;
    }
    __syncthreads();  // dump done before next overwrite
  }
}

// ---- k_phase1: zero-start chunk chains, x-temp t-major. 4 indep waves/block.
// xtemp stores restaged through swizzled LDS -> 4x 1KB dwordx4 per step.
__global__ __launch_bounds__(256) void k_phase1(
    const float* __restrict__ bb, const float* __restrict__ st,
    const float* __restrict__ eps0, const float* __restrict__ eps,
    const bf16x8* __restrict__ Wf, float* __restrict__ xtemp) {
  __shared__ float stab[16][64];
  __shared__ float btab[16][64];
  __shared__ __align__(16) unsigned char xball[4 * 16 * XB_STRIDE];
  __shared__ __align__(16) float xstage[4][16 * 64];
  int tid = threadIdx.x, w = tid >> 6, lane = tid & 63;
  unsigned char* xb = xball + w * 16 * XB_STRIDE;
  float* xs = xstage[w];
  int c = blockIdx.x >> 5;                     // 0..15
  int r0 = ((blockIdx.x & 31) * 4 + w) * 16;   // 16-row tile
  int q = lane >> 4, n15 = lane & 15;
  for (int e = tid; e < 1024; e += 256) {
    int tl = e >> 6, n = e & 63, t = c * 16 + tl;
    stab[tl][n] = st[n * 256 + t];
    btab[tl][n] = bb[t * 64 + n];
  }
  if (c == 0) {
    for (int i = 0; i < 16; ++i) {
      float v = eps0[(size_t)(r0 + i) * 64 + lane];
      *(__bf16*)(xb + i * XB_STRIDE + lane * 2) = (__bf16)v;
      xtemp[((size_t)(r0 + i)) * 64 + lane] = v;  // t=0
    }
  } else {
    for (int i = 0; i < 16; ++i)
      *(__bf16*)(xb + i * XB_STRIDE + lane * 2) = (__bf16)0.0f;
  }
  __syncthreads();  // stab/btab ready
  int t0 = (c == 0) ? 1 : c * 16;
  int t1 = c * 16 + 15;
  float epc[16], epn[16];
#pragma unroll
  for (int nt = 0; nt < 4; ++nt)
#pragma unroll
    for (int reg = 0; reg < 4; ++reg)
      epc[nt * 4 + reg] =
          eps[((size_t)(t0 - 1) * 2048 + r0 + 4 * q + reg) * 64 + nt * 16 + n15];
  for (int t = t0; t <= t1; ++t) {
    bool more = (t < t1);
    if (more) {
#pragma unroll
      for (int nt = 0; nt < 4; ++nt)
#pragma unroll
        for (int reg = 0; reg < 4; ++reg)
          epn[nt * 4 + reg] =
              eps[((size_t)t * 2048 + r0 + 4 * q + reg) * 64 + nt * 16 + n15];
    }
    bf16x8 a0 = *(const bf16x8*)(xb + n15 * XB_STRIDE + q * 16);
    bf16x8 a1 = *(const bf16x8*)(xb + n15 * XB_STRIDE + 64 + q * 16);
    f32x4 acc[4];
#pragma unroll
    for (int nt = 0; nt < 4; ++nt) {
      bf16x8 b0 = Wf[((size_t)(t * 4 + nt) * 2 + 0) * 64 + lane];
      bf16x8 b1 = Wf[((size_t)(t * 4 + nt) * 2 + 1) * 64 + lane];
      f32x4 z = {0.f, 0.f, 0.f, 0.f};
      z = __builtin_amdgcn_mfma_f32_16x16x32_bf16(a0, b0, z, 0, 0, 0);
      z = __builtin_amdgcn_mfma_f32_16x16x32_bf16(a1, b1, z, 0, 0, 0);
      acc[nt] = z;
    }
    int tl = t - c * 16;
#pragma unroll
    for (int nt = 0; nt < 4; ++nt) {
      int n = nt * 16 + n15;
      float sv = stab[tl][n];
      float bv = btab[tl][n];
#pragma unroll
      for (int reg = 0; reg < 4; ++reg) {
        int row = 4 * q + reg;
        float xn = acc[nt][reg] + bv + sv * epc[nt * 4 + reg];
        xs[SWA(row, n)] = xn;
        *(__bf16*)(xb + row * XB_STRIDE + n * 2) = (__bf16)xn;
      }
    }
    asm volatile("" ::: "memory");  // stage writes ordered before flush reads
    {
      size_t basef = ((size_t)t * 2048 + r0) * 64 + 4 * lane;
#pragma unroll
      for (int k = 0; k < 4; ++k) {
        int rr = 4 * k + (lane >> 4);
        int cc = 4 * (lane & 15);
        f32x4 v;
#pragma unroll
        for (int j = 0; j < 4; ++j) v[j] = xs[SWA(rr, cc + j)];
        *(f32x4*)(xtemp + basef + 256 * k) = v;
      }
    }
    asm volatile("" ::: "memory");  // flush reads ordered before next writes
    if (more) {
#pragma unroll
      for (int i = 0; i < 16; ++i) epc[i] = epn[i];
    }
  }
}

// ---- k_phase2: h_1 = x_15; h_{c+1} = tail_c + M_c h_c. Dumps bf16 A-frags
// hA[c] for c=1..15 (exactly the frags k_fix consumes). ----
__global__ __launch_bounds__(256) void k_phase2(const bf16x8* __restrict__ Pf,
                                                const float* __restrict__ xtemp,
                                                bf16x8* __restrict__ hA) {
  __shared__ __align__(16) unsigned char hball[4 * 16 * XB_STRIDE];
  int tid = threadIdx.x, w = tid >> 6, lane = tid & 63;
  unsigned char* hb = hball + w * 16 * XB_STRIDE;
  int rtile = blockIdx.x * 4 + w;  // 0..127
  int r0 = rtile * 16;
  int q = lane >> 4, n15 = lane & 15;
  for (int i = 0; i < 16; ++i) {
    float v = xtemp[((size_t)15 * 2048 + r0 + i) * 64 + lane];
    *(__bf16*)(hb + i * XB_STRIDE + lane * 2) = (__bf16)v;
  }
  for (int c = 1; c <= 15; ++c) {
    bf16x8 a0 = *(const bf16x8*)(hb + n15 * XB_STRIDE + q * 16);
    bf16x8 a1 = *(const bf16x8*)(hb + n15 * XB_STRIDE + 64 + q * 16);
    size_t hbase = ((size_t)(c - 1) * 128 + rtile) * 128;
    hA[hbase + lane] = a0;
    hA[hbase + 64 + lane] = a1;
    if (c == 15) break;
    f32x4 acc[4];
#pragma unroll
    for (int nt = 0; nt < 4; ++nt) {
      bf16x8 b0 = Pf[((size_t)((c - 1) * 16 + 15) * 8 + nt * 2 + 0) * 64 + lane];
      bf16x8 b1 = Pf[((size_t)((c - 1) * 16 + 15) * 8 + nt * 2 + 1) * 64 + lane];
      f32x4 z = {0.f, 0.f, 0.f, 0.f};
      z = __builtin_amdgcn_mfma_f32_16x16x32_bf16(a0, b0, z, 0, 0, 0);
      z = __builtin_amdgcn_mfma_f32_16x16x32_bf16(a1, b1, z, 0, 0, 0);
      acc[nt] = z;
    }
#pragma unroll
    for (int nt = 0; nt < 4; ++nt) {
      int n = nt * 16 + n15;
#pragma unroll
      for (int reg = 0; reg < 4; ++reg) {
        int row = 4 * q + reg;
        float tail = xtemp[((size_t)(16 * c + 15) * 2048 + r0 + row) * 64 + n];
        float hn = acc[nt][reg] + tail;
        *(__bf16*)(hb + row * XB_STRIDE + n * 2) = (__bf16)hn;
      }
    }
  }
}

// ---- k_fix: x_t += P_t * h_c. Corr restaged via swizzled LDS; RMW as
// 4x contiguous 1KB dwordx4 load/store pairs. ----
__global__ __launch_bounds__(256) void k_fix(const bf16x8* __restrict__ Pf,
                                             const bf16x8* __restrict__ hA,
                                             float* __restrict__ xtemp) {
  __shared__ __align__(16) float cst[4][16 * 64];
  int tid = threadIdx.x, w = tid >> 6, lane = tid & 63;
  float* cs = cst[w];
  int rtile = (blockIdx.x & 31) * 4 + w;  // 0..127
  int r0 = rtile * 16;
  int ct = blockIdx.x >> 5;  // 0..239
  int c1 = ct >> 4;
  int tl = ct & 15;
  int c = c1 + 1;
  int t = 16 * c + tl;
  int q = lane >> 4, n15 = lane & 15;
  size_t hbase = ((size_t)c1 * 128 + rtile) * 128;
  bf16x8 a0 = hA[hbase + lane];
  bf16x8 a1 = hA[hbase + 64 + lane];
#pragma unroll
  for (int nt = 0; nt < 4; ++nt) {
    bf16x8 b0 = Pf[((size_t)(c1 * 16 + tl) * 8 + nt * 2 + 0) * 64 + lane];
    bf16x8 b1 = Pf[((size_t)(c1 * 16 + tl) * 8 + nt * 2 + 1) * 64 + lane];
    f32x4 z = {0.f, 0.f, 0.f, 0.f};
    z = __builtin_amdgcn_mfma_f32_16x16x32_bf16(a0, b0, z, 0, 0, 0);
    z = __builtin_amdgcn_mfma_f32_16x16x32_bf16(a1, b1, z, 0, 0, 0);
#pragma unroll
    for (int reg = 0; reg < 4; ++reg)
      cs[SWA(4 * q + reg, nt * 16 + n15)] = z[reg];
  }
  asm volatile("" ::: "memory");  // stage writes ordered before flush reads
  size_t basef = ((size_t)t * 2048 + r0) * 64 + 4 * lane;
#pragma unroll
  for (int k = 0; k < 4; ++k) {
    int rr = 4 * k + (lane >> 4);
    int cc = 4 * (lane & 15);
    f32x4 cv;
#pragma unroll
    for (int j = 0; j < 4; ++j) cv[j] = cs[SWA(rr, cc + j)];
    f32x4 xv = *(const f32x4*)(xtemp + basef + 256 * k);
    xv += cv;
    *(f32x4*)(xtemp + basef + 256 * k) = xv;
  }
}

// ---- k_pack v6: wave-autonomous (t,m,n)->(m,n,255-t), LDS-staged stores.
// Stage [64][32] stride-32 + XOR swizzle: writes 2-way (free), reads merge
// to b128. One wave = one (mm, 32-t tile); no barriers (wave-private LDS).
__global__ __launch_bounds__(256) void k_pack(const float* __restrict__ stT,
                                              const float* __restrict__ eps0,
                                              const float* __restrict__ eps,
                                              const float* __restrict__ xtemp,
                                              float* __restrict__ out) {
  __shared__ __align__(16) float lds[4][64 * 32];  // 8KB per wave
  int tid = threadIdx.x;
  int w = tid >> 6, lane = tid & 63;
  float* wls = lds[w];
  int task = blockIdx.x * 4 + w;
  int tile = task >> 11;  // 0..7
  int mm = task & 2047;
  int tt0 = tile * 32;
  int iblk0 = 224 - tt0;  // output i-base of this tile's 32-float block
  int l15 = lane & 15, L = lane >> 4;
  int n0 = 4 * l15;
  // load phase: lane (l15,L) reads x/eps rows t = tt0+4r+L, n0..n0+3
  f32x4 xr[8], er[8];
#pragma unroll
  for (int r = 0; r < 8; ++r) {
    int t = tt0 + 4 * r + L;
    xr[r] = *(const f32x4*)(xtemp + ((size_t)t * 2048 + mm) * 64 + n0);
    const float* erow = (t == 0) ? (eps0 + (size_t)mm * 64)
                                 : (eps + ((size_t)(t - 1) * 2048 + mm) * 64);
    er[r] = *(const f32x4*)(erow + n0);
  }
  // m = x - s*e in original orientation (stT is t-major, L2-hot 64KB)
#pragma unroll
  for (int r = 0; r < 8; ++r) {
    int t = tt0 + 4 * r + L;
    f32x4 s = *(const f32x4*)(stT + (size_t)t * 64 + n0);
    er[r] = xr[r] - s * er[r];  // er now holds m; t=0 -> x - 1*eps0 = 0
  }
  int nrd = lane >> 3;        // read-phase row selector (0..7)
  int crd = (lane & 7) * 4;   // float offset within 32-float block
  const size_t MSOFF = (size_t)2048 * 64 * 256;
  size_t obase = ((size_t)mm * 64) * 256 + (size_t)(iblk0 + crd);
  // ---- x: stage (flip t->i) then store coalesced ----
#pragma unroll
  for (int r = 0; r < 8; ++r) {
    int col = 31 - 4 * r - L;  // i - iblk0
#pragma unroll
    for (int j = 0; j < 4; ++j) wls[SWP(n0 + j, col)] = xr[r][j];
  }
  asm volatile("" ::: "memory");  // x writes ordered before x reads
#pragma unroll
  for (int jj = 0; jj < 8; ++jj) {
    int nn = 8 * jj + nrd;
    f32x4 v;
#pragma unroll
    for (int j = 0; j < 4; ++j) v[j] = wls[SWP(nn, crd + j)];
    *(f32x4*)(out + obase + (size_t)nn * 256) = v;
  }
  asm volatile("" ::: "memory");  // x reads ordered before m writes
  // ---- m: reuse the same LDS slice (DS in-order per wave) ----
#pragma unroll
  for (int r = 0; r < 8; ++r) {
    int col = 31 - 4 * r - L;
#pragma unroll
    for (int j = 0; j < 4; ++j) wls[SWP(n0 + j, col)] = er[r][j];
  }
  asm volatile("" ::: "memory");  // m writes ordered before m reads
#pragma unroll
  for (int jj = 0; jj < 8; ++jj) {
    int nn = 8 * jj + nrd;
    f32x4 v;
#pragma unroll
    for (int j = 0; j < 4; ++j) v[j] = wls[SWP(nn, crd + j)];
    *(f32x4*)(out + MSOFF + obase + (size_t)nn * 256) = v;
  }
}

// ---- k_s: s output = table broadcast over m, t-flipped ----
__global__ __launch_bounds__(256) void k_s(const float* __restrict__ st,
                                           float* __restrict__ out) {
  int gid = blockIdx.x * 256 + threadIdx.x;  // 0..8388607
  int i0 = (gid & 63) * 4;
  int n = (gid >> 6) & 63;
  int m = gid >> 12;
  const float4 rv = *(const float4*)(st + n * 256 + 252 - i0);
  f32x4 v = {rv.w, rv.z, rv.y, rv.x};
  *(f32x4*)(out + (size_t)2 * 2048 * 64 * 256 + ((size_t)m * 64 + n) * 256 + i0) = v;
}

extern "C" void kernel_launch(void* const* d_in, const int* in_sizes, int n_in,
                              void* d_out, int out_size, void* d_ws, size_t ws_size,
                              hipStream_t stream) {
  const float* W = (const float*)d_in[0];     // (256,64,64)
  const float* bb = (const float*)d_in[1];    // (256,64)
  const float* ne = (const float*)d_in[2];    // (1,64,256)
  const float* eps0 = (const float*)d_in[3];  // (2048,64)
  const float* eps = (const float*)d_in[4];   // (255,2048,64)
  float* out = (float*)d_out;
  char* ws = (char*)d_ws;
  // ws layout: Wf 2MB | st 128KB | stT 128KB | Pf 2MB | hA 4MB  (~8.25 MB)
  bf16x8* Wf = (bf16x8*)ws;
  float* st = (float*)(ws + (size_t)(2u << 20));
  float* stT = (float*)(ws + (size_t)(2u << 20) + (128u << 10));
  bf16x8* Pf = (bf16x8*)(ws + (size_t)(2u << 20) + (256u << 10));
  bf16x8* hA = (bf16x8*)(ws + (size_t)(4u << 20) + (256u << 10));
  // x-temp (t-major, 134MB) lives in the s-output third of d_out.
  float* xtemp = out + (size_t)2 * 2048 * 64 * 256;

  hipLaunchKernelGGL(k_wf, dim3(256), dim3(256), 0, stream, W, ne, Wf, st, stT);
  hipLaunchKernelGGL(k_prefix, dim3(15), dim3(256), 0, stream, Wf, Pf);
  hipLaunchKernelGGL(k_phase1, dim3(512), dim3(256), 0, stream, bb, st, eps0, eps, Wf, xtemp);
  hipLaunchKernelGGL(k_phase2, dim3(32), dim3(256), 0, stream, Pf, xtemp, hA);
  hipLaunchKernelGGL(k_fix, dim3(7680), dim3(256), 0, stream, Pf, hA, xtemp);
  hipLaunchKernelGGL(k_pack, dim3(4096), dim3(256), 0, stream, stT, eps0, eps, xtemp, out);
  hipLaunchKernelGGL(k_s, dim3(32768), dim3(256), 0, stream, st, out);
}